// Round 5
// baseline (396.856 us; speedup 1.0000x reference)
//
#include <hip/hip_runtime.h>
#include <hip/hip_bf16.h>
#include <cstdint>

#define D_   256
#define E_   4096
#define NN_  2048

typedef float f32x4_t __attribute__((ext_vector_type(4)));
typedef short bf16x8_t __attribute__((ext_vector_type(8)));

__device__ inline short f2bf(float f) {
    union { float fv; unsigned u; } v; v.fv = f;
    unsigned r = v.u + 0x7fffu + ((v.u >> 16) & 1u);
    return (short)(r >> 16);
}

// ---------------------------------------------------------------------------
// Tiled f32 GEMM: C[M,N] = epilogue(A[M,K] @ B^T + bias)
//   OBF16: write bf16; cols < 256 additionally scaled by qsc (q pre-scaling).
// ---------------------------------------------------------------------------
template<int ACT, bool BT, bool GATHER, bool SCATTER, bool HASADD, bool OBF16>
__global__ __launch_bounds__(256)
void gemm_k(const float* __restrict__ A, const float* __restrict__ Bm,
            const float* __restrict__ bias, const float* __restrict__ addsrc,
            float* __restrict__ C, int M, int N, int K,
            const int* __restrict__ ei0, const int* __restrict__ ei1,
            const float* __restrict__ x, const float* __restrict__ eattr,
            float qsc)
{
    __shared__ float As[64][17];
    __shared__ float Bs[64][17];
    const int tid = threadIdx.x;
    const int m0 = blockIdx.x * 64;
    const int n0 = blockIdx.y * 64;
    const int ty = tid >> 4, tx = tid & 15;
    const int lrow = tid >> 2, lkq = tid & 3;
    float acc[4][4] = {};

    for (int kk = 0; kk < K; kk += 16) {
        {
            const int m = m0 + lrow;
            const int cb = kk + lkq * 4;
            const float* src;
            if (GATHER) {
                if (cb < 256)      src = x + (size_t)ei1[m] * 256 + cb;
                else if (cb < 512) src = x + (size_t)ei0[m] * 256 + (cb - 256);
                else               src = eattr + (size_t)m * 256 + (cb - 512);
            } else {
                src = A + (size_t)m * K + cb;
            }
            const float4 av = *(const float4*)src;
            As[lrow][lkq*4+0] = av.x; As[lrow][lkq*4+1] = av.y;
            As[lrow][lkq*4+2] = av.z; As[lrow][lkq*4+3] = av.w;
        }
        if (!BT) {
            const int n = n0 + lrow;
            const float4 bv = *(const float4*)(Bm + (size_t)n * K + kk + lkq * 4);
            Bs[lrow][lkq*4+0] = bv.x; Bs[lrow][lkq*4+1] = bv.y;
            Bs[lrow][lkq*4+2] = bv.z; Bs[lrow][lkq*4+3] = bv.w;
        } else {
            #pragma unroll
            for (int r = 0; r < 4; r++) {
                const int idx = tid + r * 256;
                const int kl = idx >> 6, n = idx & 63;
                Bs[n][kl] = Bm[(size_t)(kk + kl) * N + n0 + n];
            }
        }
        __syncthreads();
        #pragma unroll
        for (int k = 0; k < 16; k++) {
            float a[4], b[4];
            #pragma unroll
            for (int i = 0; i < 4; i++) a[i] = As[ty*4+i][k];
            #pragma unroll
            for (int j = 0; j < 4; j++) b[j] = Bs[tx*4+j][k];
            #pragma unroll
            for (int i = 0; i < 4; i++)
                #pragma unroll
                for (int j = 0; j < 4; j++)
                    acc[i][j] = fmaf(a[i], b[j], acc[i][j]);
        }
        __syncthreads();
    }

    #pragma unroll
    for (int i = 0; i < 4; i++) {
        const int m = m0 + ty*4 + i;
        #pragma unroll
        for (int j = 0; j < 4; j++) {
            const int n = n0 + tx*4 + j;
            float v = acc[i][j] + bias[n];
            if (ACT == 1) v = v > 0.f ? v : 0.2f * v;
            if (HASADD) v += addsrc[(size_t)m * N + n];
            if (SCATTER) {
                atomicAdd(&C[(size_t)ei1[m] * N + n], v);
            } else if (OBF16) {
                const float vv = (n < 256) ? v * qsc : v;
                ((short*)C)[(size_t)m * N + n] = f2bf(vv);
            } else {
                C[(size_t)m * N + n] = v;
            }
        }
    }
}

// ---------------------------------------------------------------------------
// Mask dtype detection + bit packing (validated round 2).
// ---------------------------------------------------------------------------
__global__ __launch_bounds__(256)
void detect_mask_k(const unsigned int* __restrict__ m, int* __restrict__ flag)
{
    __shared__ int bad;
    if (threadIdx.x == 0) bad = 0;
    __syncthreads();
    int mybad = 0;
    #pragma unroll
    for (int i = 0; i < 32; i++)
        if (m[threadIdx.x + i * 256] > 1u) mybad = 1;
    if (mybad) atomicOr(&bad, 1);
    __syncthreads();
    if (threadIdx.x == 0) *flag = bad ? 0 : 1;
}

__global__ __launch_bounds__(256)
void pack_mask_k(const unsigned char* __restrict__ mraw,
                 unsigned int* __restrict__ pm, const int* __restrict__ flag)
{
    const int t = blockIdx.x * 256 + threadIdx.x;
    const int row = t >> 7, wb = t & 127;
    unsigned int bits = 0;
    if (*flag) {
        const uint4* p = (const uint4*)((const int*)mraw + (size_t)row * 4096 + wb * 32);
        #pragma unroll
        for (int g = 0; g < 8; g++) {
            const uint4 v = p[g];
            if (v.x) bits |= 1u << (g*4+0);
            if (v.y) bits |= 1u << (g*4+1);
            if (v.z) bits |= 1u << (g*4+2);
            if (v.w) bits |= 1u << (g*4+3);
        }
    } else {
        const uint4* p = (const uint4*)(mraw + (size_t)row * 4096 + wb * 32);
        #pragma unroll
        for (int g = 0; g < 2; g++) {
            const uint4 v = p[g];
            const unsigned int u[4] = {v.x, v.y, v.z, v.w};
            #pragma unroll
            for (int b2 = 0; b2 < 4; b2++)
                #pragma unroll
                for (int by = 0; by < 4; by++)
                    if ((u[b2] >> (8*by)) & 0xffu) bits |= 1u << (g*16 + b2*4 + by);
        }
    }
    pm[t] = bits;
}

// ---------------------------------------------------------------------------
// V pre-transpose: vt[head][d=32][key=4096] bf16 from qkv V-part.
// Grid 8 heads x 64 key-tiles, 256 threads.
// ---------------------------------------------------------------------------
__global__ __launch_bounds__(256)
void vtrans_k(const short* __restrict__ qkvb, short* __restrict__ vt)
{
    __shared__ short Ts[64][40];   // row 80 B (16B-aligned rows), padded
    const int head = blockIdx.x >> 6;
    const int k0 = (blockIdx.x & 63) * 64;
    const int tid = threadIdx.x;
    const int skey = tid >> 2, sc = tid & 3;
    const bf16x8_t v = *(const bf16x8_t*)(qkvb + (size_t)(k0 + skey)*768 + 512 + head*32 + sc*8);
    *(bf16x8_t*)(&Ts[skey][sc*8]) = v;
    __syncthreads();
    const int sd = tid >> 3, skc = tid & 7;
    short outv[8];
    #pragma unroll
    for (int j = 0; j < 8; j++) outv[j] = Ts[skc*8 + j][sd];
    *(bf16x8_t*)(vt + (size_t)head*131072 + (size_t)sd*4096 + k0 + skc*8) = *(bf16x8_t*)outv;
}

// ---------------------------------------------------------------------------
// MFMA bf16 flash attention, intra-block split-K.
// Block = 64 queries x 1 head, 16 waves (1024 thr): 4 key-groups (gi) of
// 4 q-waves (wq). Group gi processes keys [gi*1024, gi*1024+1024) in 16
// tiles of 64, producing partial (m,l,O); merged through LDS at the end.
// Grid: 8 heads * 64 q-blocks = 512 blocks -> 2 blocks/CU * 16 waves = 100%.
// LDS (64 KB): per-group K tile [64k][32d] + Vt tile [32d][64k] at gi*8192;
//              per-wave P tile [16q][64k] at 32768 + wave*2048.
// Merge overlays: Om[wave][lane][8f32] at 0 (32 KB); Ml at 32768 (2 KB).
// All tiles full-address XOR-swizzled, same involution on write and read.
// Q is pre-scaled by 1/sqrt(32) in the qkv GEMM epilogue.
// ---------------------------------------------------------------------------
__global__ __launch_bounds__(1024, 8)
void attn_k(const short* __restrict__ qkvb, const short* __restrict__ vt,
            const unsigned int* __restrict__ pmask, float* __restrict__ o)
{
    __shared__ char lds[65536];
    const int tid = threadIdx.x;
    const int wave = tid >> 6, l = tid & 63;
    const int g = l >> 4, ln = l & 15;
    const int gi = wave >> 2, wq = wave & 3;
    const int head = blockIdx.x >> 6;
    const int q0 = (blockIdx.x & 63) * 64;
    const int qw = q0 + wq * 16;

    // Q A-frag (pre-scaled): query qw+ln, dims g*8..g*8+7
    const bf16x8_t qf = *(const bf16x8_t*)(qkvb + (size_t)(qw + ln)*768 + head*32 + g*8);

    f32x4_t oacc0 = {0.f,0.f,0.f,0.f};
    f32x4_t oacc1 = {0.f,0.f,0.f,0.f};
    float mrun[4] = {-1e30f,-1e30f,-1e30f,-1e30f};
    float lrun[4] = {0.f,0.f,0.f,0.f};

    // staging roles within the 256-thread group
    const int st = tid & 255;
    const int skey = st >> 2, sc = st & 3;   // K: one key row, 8 dims
    const int sd = st >> 3, skc = st & 7;    // V: one d row, 8 keys
    char* Kg = lds + gi*8192;
    char* Vg = lds + gi*8192 + 4096;
    char* Pw = lds + 32768 + wave*2048;
    const short* kgp = qkvb + 256 + head*32 + sc*8;
    const short* vgp = vt + (size_t)head*131072 + (size_t)sd*4096;

    for (int t = 0; t < 16; t++) {
        const int k0 = gi*1024 + t*64;
        __syncthreads();
        {   // stage K + Vt for this group's tile (all b128, swizzled)
            const bf16x8_t kv = *(const bf16x8_t*)(kgp + (size_t)(k0 + skey)*768);
            *(bf16x8_t*)(Kg + ((skey*64 + sc*16) ^ ((skey & 7) << 4))) = kv;
            const bf16x8_t vv = *(const bf16x8_t*)(vgp + k0 + skc*8);
            *(bf16x8_t*)(Vg + ((sd*128 + skc*16) ^ ((sd & 7) << 4))) = vv;
        }
        __syncthreads();

        // QK^T: 4 key sub-tiles -> C-frags (col=key=ln, rows g*4+r)
        f32x4_t s[4];
        #pragma unroll
        for (int kt = 0; kt < 4; kt++) {
            const int key = kt*16 + ln;
            const bf16x8_t kf = *(const bf16x8_t*)(Kg + ((key*64 + g*16) ^ ((key & 7) << 4)));
            f32x4_t z = {0.f,0.f,0.f,0.f};
            s[kt] = __builtin_amdgcn_mfma_f32_16x16x32_bf16(qf, kf, z, 0, 0, 0);
        }

        // online softmax per q-row; max over RAW scores (exact: common shift),
        // mask applied post-exp (hard zero).
        #pragma unroll
        for (int r = 0; r < 4; r++) {
            const int qa = qw + g*4 + r;
            const uint2 mw = *(const uint2*)(pmask + (size_t)qa * 128 + (k0 >> 5));
            const float s0 = s[0][r], s1 = s[1][r], s2 = s[2][r], s3 = s[3][r];
            float tmax = fmaxf(fmaxf(s0, s1), fmaxf(s2, s3));
            tmax = fmaxf(tmax, __shfl_xor(tmax, 1));
            tmax = fmaxf(tmax, __shfl_xor(tmax, 2));
            tmax = fmaxf(tmax, __shfl_xor(tmax, 4));
            tmax = fmaxf(tmax, __shfl_xor(tmax, 8));
            const float mnew = fmaxf(mrun[r], tmax);
            const float f = __expf(mrun[r] - mnew);
            mrun[r] = mnew;
            const float p0 = ((mw.x >> ln)        & 1u) ? __expf(s0 - mnew) : 0.f;
            const float p1 = ((mw.x >> (16 + ln)) & 1u) ? __expf(s1 - mnew) : 0.f;
            const float p2 = ((mw.y >> ln)        & 1u) ? __expf(s2 - mnew) : 0.f;
            const float p3 = ((mw.y >> (16 + ln)) & 1u) ? __expf(s3 - mnew) : 0.f;
            float ps = (p0 + p1) + (p2 + p3);
            ps += __shfl_xor(ps, 1);
            ps += __shfl_xor(ps, 2);
            ps += __shfl_xor(ps, 4);
            ps += __shfl_xor(ps, 8);
            lrun[r] = lrun[r] * f + ps;
            oacc0[r] *= f;
            oacc1[r] *= f;
            // P row write (full-address swizzle, same formula as PV read)
            const int base = (g*4 + r) * 128;
            const int swz = ((g*4 + r) & 7) << 4;
            *(short*)(Pw + ((base + (ln +  0)*2) ^ swz)) = f2bf(p0);
            *(short*)(Pw + ((base + (ln + 16)*2) ^ swz)) = f2bf(p1);
            *(short*)(Pw + ((base + (ln + 32)*2) ^ swz)) = f2bf(p2);
            *(short*)(Pw + ((base + (ln + 48)*2) ^ swz)) = f2bf(p3);
        }

        // PV: O += P.V
        #pragma unroll
        for (int kh = 0; kh < 2; kh++) {
            const bf16x8_t pf = *(const bf16x8_t*)(Pw + ((ln*128 + kh*64 + g*16) ^ ((ln & 7) << 4)));
            {
                const int d = ln;
                const bf16x8_t vf = *(const bf16x8_t*)(Vg + ((d*128 + kh*64 + g*16) ^ ((d & 7) << 4)));
                oacc0 = __builtin_amdgcn_mfma_f32_16x16x32_bf16(pf, vf, oacc0, 0, 0, 0);
            }
            {
                const int d = 16 + ln;
                const bf16x8_t vf = *(const bf16x8_t*)(Vg + ((d*128 + kh*64 + g*16) ^ ((d & 7) << 4)));
                oacc1 = __builtin_amdgcn_mfma_f32_16x16x32_bf16(pf, vf, oacc1, 0, 0, 0);
            }
        }
    }

    // ---- merge the 4 key-group partials (same q rows across gi) ----
    __syncthreads();
    *(f32x4_t*)(lds + wave*2048 + l*32)      = oacc0;
    *(f32x4_t*)(lds + wave*2048 + l*32 + 16) = oacc1;
    if (ln == 0) {
        float2* mlp = (float2*)(lds + 32768 + (wave*16 + g*4)*8);
        #pragma unroll
        for (int r = 0; r < 4; r++) mlp[r] = float2{mrun[r], lrun[r]};
    }
    __syncthreads();
    if (gi == 0) {
        float M[4] = {-1e30f,-1e30f,-1e30f,-1e30f};
        #pragma unroll
        for (int sg = 0; sg < 4; sg++) {
            const float2* mlp = (const float2*)(lds + 32768 + ((sg*4 + wq)*16 + g*4)*8);
            #pragma unroll
            for (int r = 0; r < 4; r++) M[r] = fmaxf(M[r], mlp[r].x);
        }
        f32x4_t O0 = {0.f,0.f,0.f,0.f}, O1 = {0.f,0.f,0.f,0.f};
        float L[4] = {0.f,0.f,0.f,0.f};
        #pragma unroll
        for (int sg = 0; sg < 4; sg++) {
            const int wsrc = sg*4 + wq;
            const float2* mlp = (const float2*)(lds + 32768 + (wsrc*16 + g*4)*8);
            const f32x4_t a0 = *(const f32x4_t*)(lds + wsrc*2048 + l*32);
            const f32x4_t a1 = *(const f32x4_t*)(lds + wsrc*2048 + l*32 + 16);
            #pragma unroll
            for (int r = 0; r < 4; r++) {
                const float wgt = __expf(mlp[r].x - M[r]);
                L[r] += wgt * mlp[r].y;
                O0[r] += wgt * a0[r];
                O1[r] += wgt * a1[r];
            }
        }
        #pragma unroll
        for (int r = 0; r < 4; r++) {
            const float inv = 1.0f / fmaxf(L[r], 1e-37f);
            const int qa = q0 + wq*16 + g*4 + r;
            o[(size_t)qa * 256 + head*32 +  0 + ln] = O0[r] * inv;
            o[(size_t)qa * 256 + head*32 + 16 + ln] = O1[r] * inv;
        }
    }
}

// ---------------------------------------------------------------------------
// LayerNorm over 256 dims, one block per row.
// ---------------------------------------------------------------------------
__global__ __launch_bounds__(256)
void ln_k(const float* __restrict__ in, const float* __restrict__ g,
          const float* __restrict__ b, float* __restrict__ out)
{
    const int n = blockIdx.x, t = threadIdx.x;
    const float v = in[(size_t)n * 256 + t];
    float s1 = v, s2 = v * v;
    #pragma unroll
    for (int off = 32; off > 0; off >>= 1) {
        s1 += __shfl_xor(s1, off);
        s2 += __shfl_xor(s2, off);
    }
    __shared__ float r1[4], r2[4];
    const int wv = t >> 6;
    if ((t & 63) == 0) { r1[wv] = s1; r2[wv] = s2; }
    __syncthreads();
    const float t1 = r1[0] + r1[1] + r1[2] + r1[3];
    const float t2 = r2[0] + r2[1] + r2[2] + r2[3];
    const float mu  = t1 * (1.0f / 256.0f);
    const float var = t2 * (1.0f / 256.0f) - mu * mu;
    const float rs  = rsqrtf(var + 1e-5f);
    out[(size_t)n * 256 + t] = (v - mu) * rs * g[t] + b[t];
}

// ---------------------------------------------------------------------------
extern "C" void kernel_launch(void* const* d_in, const int* in_sizes, int n_in,
                              void* d_out, int out_size, void* d_ws, size_t ws_size,
                              hipStream_t stream)
{
    const float* x     = (const float*)d_in[0];
    const int*   ei    = (const int*)  d_in[1];
    const float* eattr = (const float*)d_in[2];
    const unsigned char* mask = (const unsigned char*)d_in[3];
    const float* W1   = (const float*)d_in[4];
    const float* b1   = (const float*)d_in[5];
    const float* W2   = (const float*)d_in[6];
    const float* b2   = (const float*)d_in[7];
    const float* ipw  = (const float*)d_in[8];
    const float* ipb  = (const float*)d_in[9];
    const float* ow   = (const float*)d_in[10];
    const float* ob   = (const float*)d_in[11];
    const float* root = (const float*)d_in[12];
    const float* bp   = (const float*)d_in[13];
    const float* ln1g = (const float*)d_in[14];
    const float* ln1b = (const float*)d_in[15];
    const float* ln2g = (const float*)d_in[16];
    const float* ln2b = (const float*)d_in[17];
    const float* linw = (const float*)d_in[18];
    const float* linb = (const float*)d_in[19];
    const int* ei0 = ei;
    const int* ei1 = ei + E_;

    float* ws = (float*)d_ws;
    float* h1    = ws;                              // [E,256]; later attn o; later z
    float* h     = ws + 1048576;                    // [E,256]; later y1
    short* qkvb  = (short*)(ws + 2097152);          // [E,768] bf16 (q pre-scaled)
    float* aggr  = ws + 3670016;                    // [N,256]
    float* outb  = ws + 4194304;                    // [N,256]
    unsigned int* pmask = (unsigned int*)(ws + 4718592);  // [4096][128] bits
    int* flag    = (int*)(ws + 5242880);
    short* vt    = (short*)(ws + 5242896);          // [8][32][4096] bf16
    float* o    = h1;
    float* y1   = h;
    float* z    = h1;

    hipMemsetAsync(aggr, 0, (size_t)NN_ * D_ * sizeof(float), stream);

    dim3 blk(256);
    detect_mask_k<<<dim3(1), blk, 0, stream>>>((const unsigned int*)mask, flag);
    pack_mask_k<<<dim3(2048), blk, 0, stream>>>(mask, pmask, flag);

    // S1: h1 = leakyrelu(cat(x_i,x_j,eattr) @ W1^T + b1)
    gemm_k<1,false,true,false,false,false><<<dim3(64,4), blk, 0, stream>>>(
        nullptr, W1, b1, nullptr, h1, E_, 256, 768, ei0, ei1, x, eattr, 1.0f);
    // S2: h = h1 @ W2^T + b2
    gemm_k<0,false,false,false,false,false><<<dim3(64,4), blk, 0, stream>>>(
        h1, W2, b2, nullptr, h, E_, 256, 256, nullptr, nullptr, nullptr, nullptr, 1.0f);
    // S3: qkvb = bf16(h @ in_proj_w^T + in_proj_b), q-part scaled by 1/sqrt(32)
    gemm_k<0,false,false,false,false,true><<<dim3(64,12), blk, 0, stream>>>(
        h, ipw, ipb, nullptr, (float*)qkvb, E_, 768, 256, nullptr, nullptr, nullptr, nullptr,
        0.17677669529663687f);
    // V transpose: vt[head][d][key]
    vtrans_k<<<dim3(512), blk, 0, stream>>>(qkvb, vt);
    // S4: MFMA flash attention (intra-block split-K) -> o (f32)
    attn_k<<<dim3(512), dim3(1024), 0, stream>>>(qkvb, vt, pmask, o);
    // S5: msg = o @ out_w^T + out_b, scatter-add to aggr[target]
    gemm_k<0,false,false,true,false,false><<<dim3(64,4), blk, 0, stream>>>(
        o, ow, ob, nullptr, aggr, E_, 256, 256, nullptr, ei1, nullptr, nullptr, 1.0f);
    // S6: out = x @ root + aggr + bias_p
    gemm_k<0,true,false,false,true,false><<<dim3(32,4), blk, 0, stream>>>(
        x, root, bp, aggr, outb, NN_, 256, 256, nullptr, nullptr, nullptr, nullptr, 1.0f);
    // LN1
    ln_k<<<dim3(2048), blk, 0, stream>>>(outb, ln1g, ln1b, y1);
    // F2: z = y1 + y1 @ lin_w^T + lin_b
    gemm_k<0,false,false,false,true,false><<<dim3(32,4), blk, 0, stream>>>(
        y1, linw, linb, y1, z, NN_, 256, 256, nullptr, nullptr, nullptr, nullptr, 1.0f);
    // LN2 -> out
    ln_k<<<dim3(2048), blk, 0, stream>>>(z, ln2g, ln2b, (float*)d_out);
}

// Round 6
// 312.433 us; speedup vs baseline: 1.2702x; 1.2702x over previous
//
#include <hip/hip_runtime.h>
#include <hip/hip_bf16.h>
#include <cstdint>

#define D_   256
#define E_   4096
#define NN_  2048

typedef float f32x4_t __attribute__((ext_vector_type(4)));
typedef short bf16x8_t __attribute__((ext_vector_type(8)));

__device__ inline short f2bf(float f) {
    union { float fv; unsigned u; } v; v.fv = f;
    unsigned r = v.u + 0x7fffu + ((v.u >> 16) & 1u);
    return (short)(r >> 16);
}

__device__ inline unsigned cvtpk_bf16(float lo, float hi) {
    unsigned r;
    asm("v_cvt_pk_bf16_f32 %0, %1, %2" : "=v"(r) : "v"(lo), "v"(hi));
    return r;
}

// ---------------------------------------------------------------------------
// Tiled f32 GEMM: C[M,N] = epilogue(A[M,K] @ B^T + bias)
//   OBF16: write bf16; cols < 256 additionally scaled by qsc (q pre-scaling).
// ---------------------------------------------------------------------------
template<int ACT, bool BT, bool GATHER, bool SCATTER, bool HASADD, bool OBF16>
__global__ __launch_bounds__(256)
void gemm_k(const float* __restrict__ A, const float* __restrict__ Bm,
            const float* __restrict__ bias, const float* __restrict__ addsrc,
            float* __restrict__ C, int M, int N, int K,
            const int* __restrict__ ei0, const int* __restrict__ ei1,
            const float* __restrict__ x, const float* __restrict__ eattr,
            float qsc)
{
    __shared__ float As[64][17];
    __shared__ float Bs[64][17];
    const int tid = threadIdx.x;
    const int m0 = blockIdx.x * 64;
    const int n0 = blockIdx.y * 64;
    const int ty = tid >> 4, tx = tid & 15;
    const int lrow = tid >> 2, lkq = tid & 3;
    float acc[4][4] = {};

    for (int kk = 0; kk < K; kk += 16) {
        {
            const int m = m0 + lrow;
            const int cb = kk + lkq * 4;
            const float* src;
            if (GATHER) {
                if (cb < 256)      src = x + (size_t)ei1[m] * 256 + cb;
                else if (cb < 512) src = x + (size_t)ei0[m] * 256 + (cb - 256);
                else               src = eattr + (size_t)m * 256 + (cb - 512);
            } else {
                src = A + (size_t)m * K + cb;
            }
            const float4 av = *(const float4*)src;
            As[lrow][lkq*4+0] = av.x; As[lrow][lkq*4+1] = av.y;
            As[lrow][lkq*4+2] = av.z; As[lrow][lkq*4+3] = av.w;
        }
        if (!BT) {
            const int n = n0 + lrow;
            const float4 bv = *(const float4*)(Bm + (size_t)n * K + kk + lkq * 4);
            Bs[lrow][lkq*4+0] = bv.x; Bs[lrow][lkq*4+1] = bv.y;
            Bs[lrow][lkq*4+2] = bv.z; Bs[lrow][lkq*4+3] = bv.w;
        } else {
            #pragma unroll
            for (int r = 0; r < 4; r++) {
                const int idx = tid + r * 256;
                const int kl = idx >> 6, n = idx & 63;
                Bs[n][kl] = Bm[(size_t)(kk + kl) * N + n0 + n];
            }
        }
        __syncthreads();
        #pragma unroll
        for (int k = 0; k < 16; k++) {
            float a[4], b[4];
            #pragma unroll
            for (int i = 0; i < 4; i++) a[i] = As[ty*4+i][k];
            #pragma unroll
            for (int j = 0; j < 4; j++) b[j] = Bs[tx*4+j][k];
            #pragma unroll
            for (int i = 0; i < 4; i++)
                #pragma unroll
                for (int j = 0; j < 4; j++)
                    acc[i][j] = fmaf(a[i], b[j], acc[i][j]);
        }
        __syncthreads();
    }

    #pragma unroll
    for (int i = 0; i < 4; i++) {
        const int m = m0 + ty*4 + i;
        #pragma unroll
        for (int j = 0; j < 4; j++) {
            const int n = n0 + tx*4 + j;
            float v = acc[i][j] + bias[n];
            if (ACT == 1) v = v > 0.f ? v : 0.2f * v;
            if (HASADD) v += addsrc[(size_t)m * N + n];
            if (SCATTER) {
                atomicAdd(&C[(size_t)ei1[m] * N + n], v);
            } else if (OBF16) {
                const float vv = (n < 256) ? v * qsc : v;
                ((short*)C)[(size_t)m * N + n] = f2bf(vv);
            } else {
                C[(size_t)m * N + n] = v;
            }
        }
    }
}

// ---------------------------------------------------------------------------
// Mask dtype detection + bit packing (validated round 2).
// ---------------------------------------------------------------------------
__global__ __launch_bounds__(256)
void detect_mask_k(const unsigned int* __restrict__ m, int* __restrict__ flag)
{
    __shared__ int bad;
    if (threadIdx.x == 0) bad = 0;
    __syncthreads();
    int mybad = 0;
    #pragma unroll
    for (int i = 0; i < 32; i++)
        if (m[threadIdx.x + i * 256] > 1u) mybad = 1;
    if (mybad) atomicOr(&bad, 1);
    __syncthreads();
    if (threadIdx.x == 0) *flag = bad ? 0 : 1;
}

__global__ __launch_bounds__(256)
void pack_mask_k(const unsigned char* __restrict__ mraw,
                 unsigned int* __restrict__ pm, const int* __restrict__ flag)
{
    const int t = blockIdx.x * 256 + threadIdx.x;
    const int row = t >> 7, wb = t & 127;
    unsigned int bits = 0;
    if (*flag) {
        const uint4* p = (const uint4*)((const int*)mraw + (size_t)row * 4096 + wb * 32);
        #pragma unroll
        for (int g = 0; g < 8; g++) {
            const uint4 v = p[g];
            if (v.x) bits |= 1u << (g*4+0);
            if (v.y) bits |= 1u << (g*4+1);
            if (v.z) bits |= 1u << (g*4+2);
            if (v.w) bits |= 1u << (g*4+3);
        }
    } else {
        const uint4* p = (const uint4*)(mraw + (size_t)row * 4096 + wb * 32);
        #pragma unroll
        for (int g = 0; g < 2; g++) {
            const uint4 v = p[g];
            const unsigned int u[4] = {v.x, v.y, v.z, v.w};
            #pragma unroll
            for (int b2 = 0; b2 < 4; b2++)
                #pragma unroll
                for (int by = 0; by < 4; by++)
                    if ((u[b2] >> (8*by)) & 0xffu) bits |= 1u << (g*16 + b2*4 + by);
        }
    }
    pm[t] = bits;
}

// ---------------------------------------------------------------------------
// V pre-transpose: vt[head][d=32][key=4096] bf16 from qkv V-part.
// ---------------------------------------------------------------------------
__global__ __launch_bounds__(256)
void vtrans_k(const short* __restrict__ qkvb, short* __restrict__ vt)
{
    __shared__ short Ts[64][40];
    const int head = blockIdx.x >> 6;
    const int k0 = (blockIdx.x & 63) * 64;
    const int tid = threadIdx.x;
    const int skey = tid >> 2, sc = tid & 3;
    const bf16x8_t v = *(const bf16x8_t*)(qkvb + (size_t)(k0 + skey)*768 + 512 + head*32 + sc*8);
    *(bf16x8_t*)(&Ts[skey][sc*8]) = v;
    __syncthreads();
    const int sd = tid >> 3, skc = tid & 7;
    short outv[8];
    #pragma unroll
    for (int j = 0; j < 8; j++) outv[j] = Ts[skc*8 + j][sd];
    *(bf16x8_t*)(vt + (size_t)head*131072 + (size_t)sd*4096 + k0 + skc*8) = *(bf16x8_t*)outv;
}

// ---------------------------------------------------------------------------
// MFMA bf16 flash attention v2: swapped QK^T + fixed-shift softmax.
// Block = 64 q x 1 head, 4 waves (16 q each). Grid 512. Sequential k-sweep
// (L2-friendly), double-buffered K/V staging (prefetch before compute).
//
// S^T = mfma(A=K, B=Q): C[row=key][col=q] -> lane (g,ln) owns q-col ln,
// keys kt*16+g*4+r. Fixed shift: p = mask ? exp(s-12) : 0 (softmax is
// shift-invariant; normalize by l=sum(p) at the end -> per-tile max/rescale
// chain eliminated; only += accumulators cross tiles).
// P stored per-wave LDS [16 q][64 key] bf16 linear, row-XOR ^((q&7)<<4):
// byte = (q*128 + key*2) ^ swz; write b64 per kt, read b128 per kh.
// PV: O^T = mfma(A=Vt, B=P): C[row=d][col=q] -> float4 epilogue stores.
// lsum reduced across g-lanes ONCE at the end (2 shuffles).
// LDS: K dbuf 2x4KB @0, Vt dbuf 2x4KB @8192, P 4x2KB @16384. Total 24KB.
// ---------------------------------------------------------------------------
__global__ __launch_bounds__(256)
void attn_k(const short* __restrict__ qkvb, const short* __restrict__ vt,
            const unsigned int* __restrict__ pmask, float* __restrict__ o)
{
    __shared__ char lds[24576];
    const int tid = threadIdx.x;
    const int w = tid >> 6, l = tid & 63;
    const int g = l >> 4, ln = l & 15;
    const int head = blockIdx.x >> 6;
    const int q0 = (blockIdx.x & 63) * 64;
    const int qa = q0 + w * 16 + ln;          // this lane's q column

    // Q B-frag (pre-scaled by 1/sqrt(32) in S3): col=q=ln, k-dims g*8..+7
    const bf16x8_t qf = *(const bf16x8_t*)(qkvb + (size_t)qa*768 + head*32 + g*8);

    f32x4_t oT0 = {0.f,0.f,0.f,0.f};   // O^T: rows d=g*4+reg, col q=ln
    f32x4_t oT1 = {0.f,0.f,0.f,0.f};   // rows d=16+g*4+reg
    float lsum = 0.f;

    const int skey = tid >> 2, sc = tid & 3;   // K staging role
    const int sd = tid >> 3, skc = tid & 7;    // V staging role
    const short* kgp = qkvb + 256 + head*32 + sc*8;
    const short* vgp = vt + (size_t)head*131072 + (size_t)sd*4096 + skc*8;
    char* Pw = lds + 16384 + w*2048;
    const unsigned int* mrow = pmask + (size_t)qa*128;
    const int kswz = (skey & 7) << 4, vswz = (sd & 7) << 4;
    const int pswz = (ln & 7) << 4;

    {   // stage tile 0 -> buf 0
        const bf16x8_t kv = *(const bf16x8_t*)(kgp + (size_t)skey*768);
        *(bf16x8_t*)(lds + ((skey*64 + sc*16) ^ kswz)) = kv;
        const bf16x8_t vv = *(const bf16x8_t*)(vgp);
        *(bf16x8_t*)(lds + 8192 + ((sd*128 + skc*16) ^ vswz)) = vv;
    }

    for (int t = 0; t < 64; ++t) {
        __syncthreads();
        const int cur = t & 1;
        if (t < 63) {   // prefetch next tile into the other buffer
            const int k0n = (t + 1) * 64;
            const bf16x8_t kv = *(const bf16x8_t*)(kgp + (size_t)(k0n + skey)*768);
            *(bf16x8_t*)(lds + (cur^1)*4096 + ((skey*64 + sc*16) ^ kswz)) = kv;
            const bf16x8_t vv = *(const bf16x8_t*)(vgp + k0n);
            *(bf16x8_t*)(lds + 8192 + (cur^1)*4096 + ((sd*128 + skc*16) ^ vswz)) = vv;
        }
        char* Kb = lds + cur*4096;
        char* Vb = lds + 8192 + cur*4096;

        // S^T: 4 MFMAs over key sub-tiles (A=K rows=keys, B=Q col=q)
        f32x4_t s[4];
        #pragma unroll
        for (int kt = 0; kt < 4; kt++) {
            const int key = kt*16 + ln;
            const bf16x8_t kf = *(const bf16x8_t*)(Kb + ((key*64 + g*16) ^ ((key & 7) << 4)));
            f32x4_t z = {0.f,0.f,0.f,0.f};
            s[kt] = __builtin_amdgcn_mfma_f32_16x16x32_bf16(kf, qf, z, 0, 0, 0);
        }

        // fixed-shift masked exp; accumulate lsum; pack P -> LDS (b64/kt)
        const uint2 mw = *(const uint2*)(mrow + t*2);
        #pragma unroll
        for (int kt = 0; kt < 4; kt++) {
            const unsigned word = (kt < 2) ? mw.x : mw.y;
            float p[4];
            #pragma unroll
            for (int r = 0; r < 4; r++) {
                const float e = __expf(s[kt][r] - 12.0f);
                p[r] = ((word >> ((kt & 1)*16 + g*4 + r)) & 1u) ? e : 0.f;
            }
            lsum += (p[0] + p[1]) + (p[2] + p[3]);
            uint2 pk;
            pk.x = cvtpk_bf16(p[0], p[1]);
            pk.y = cvtpk_bf16(p[2], p[3]);
            *(uint2*)(Pw + ((ln*128 + kt*32 + g*8) ^ pswz)) = pk;
        }

        // PV: O^T += Vt . P   (A=Vt rows=d, B=P col=q)
        #pragma unroll
        for (int kh = 0; kh < 2; kh++) {
            const bf16x8_t pf = *(const bf16x8_t*)(Pw + ((ln*128 + kh*64 + g*16) ^ pswz));
            const bf16x8_t vf0 = *(const bf16x8_t*)(Vb + ((ln*128 + kh*64 + g*16) ^ pswz));
            const bf16x8_t vf1 = *(const bf16x8_t*)(Vb + (((16+ln)*128 + kh*64 + g*16) ^ pswz));
            oT0 = __builtin_amdgcn_mfma_f32_16x16x32_bf16(vf0, pf, oT0, 0, 0, 0);
            oT1 = __builtin_amdgcn_mfma_f32_16x16x32_bf16(vf1, pf, oT1, 0, 0, 0);
        }
    }

    // final: reduce lsum across the 4 g-lanes of this q, normalize, store
    lsum += __shfl_xor(lsum, 16);
    lsum += __shfl_xor(lsum, 32);
    const float inv = 1.0f / fmaxf(lsum, 1e-37f);
    float* op = o + (size_t)qa * 256 + head*32;
    float4 v0 = {oT0[0]*inv, oT0[1]*inv, oT0[2]*inv, oT0[3]*inv};
    float4 v1 = {oT1[0]*inv, oT1[1]*inv, oT1[2]*inv, oT1[3]*inv};
    *(float4*)(op + g*4) = v0;
    *(float4*)(op + 16 + g*4) = v1;
}

// ---------------------------------------------------------------------------
// LayerNorm over 256 dims, one block per row.
// ---------------------------------------------------------------------------
__global__ __launch_bounds__(256)
void ln_k(const float* __restrict__ in, const float* __restrict__ g,
          const float* __restrict__ b, float* __restrict__ out)
{
    const int n = blockIdx.x, t = threadIdx.x;
    const float v = in[(size_t)n * 256 + t];
    float s1 = v, s2 = v * v;
    #pragma unroll
    for (int off = 32; off > 0; off >>= 1) {
        s1 += __shfl_xor(s1, off);
        s2 += __shfl_xor(s2, off);
    }
    __shared__ float r1[4], r2[4];
    const int wv = t >> 6;
    if ((t & 63) == 0) { r1[wv] = s1; r2[wv] = s2; }
    __syncthreads();
    const float t1 = r1[0] + r1[1] + r1[2] + r1[3];
    const float t2 = r2[0] + r2[1] + r2[2] + r2[3];
    const float mu  = t1 * (1.0f / 256.0f);
    const float var = t2 * (1.0f / 256.0f) - mu * mu;
    const float rs  = rsqrtf(var + 1e-5f);
    out[(size_t)n * 256 + t] = (v - mu) * rs * g[t] + b[t];
}

// ---------------------------------------------------------------------------
extern "C" void kernel_launch(void* const* d_in, const int* in_sizes, int n_in,
                              void* d_out, int out_size, void* d_ws, size_t ws_size,
                              hipStream_t stream)
{
    const float* x     = (const float*)d_in[0];
    const int*   ei    = (const int*)  d_in[1];
    const float* eattr = (const float*)d_in[2];
    const unsigned char* mask = (const unsigned char*)d_in[3];
    const float* W1   = (const float*)d_in[4];
    const float* b1   = (const float*)d_in[5];
    const float* W2   = (const float*)d_in[6];
    const float* b2   = (const float*)d_in[7];
    const float* ipw  = (const float*)d_in[8];
    const float* ipb  = (const float*)d_in[9];
    const float* ow   = (const float*)d_in[10];
    const float* ob   = (const float*)d_in[11];
    const float* root = (const float*)d_in[12];
    const float* bp   = (const float*)d_in[13];
    const float* ln1g = (const float*)d_in[14];
    const float* ln1b = (const float*)d_in[15];
    const float* ln2g = (const float*)d_in[16];
    const float* ln2b = (const float*)d_in[17];
    const float* linw = (const float*)d_in[18];
    const float* linb = (const float*)d_in[19];
    const int* ei0 = ei;
    const int* ei1 = ei + E_;

    float* ws = (float*)d_ws;
    float* h1    = ws;                              // [E,256]; later attn o; later z
    float* h     = ws + 1048576;                    // [E,256]; later y1
    short* qkvb  = (short*)(ws + 2097152);          // [E,768] bf16 (q pre-scaled)
    float* aggr  = ws + 3670016;                    // [N,256]
    float* outb  = ws + 4194304;                    // [N,256]
    unsigned int* pmask = (unsigned int*)(ws + 4718592);  // [4096][128] bits
    int* flag    = (int*)(ws + 5242880);
    short* vt    = (short*)(ws + 5242896);          // [8][32][4096] bf16
    float* o    = h1;
    float* y1   = h;
    float* z    = h1;

    hipMemsetAsync(aggr, 0, (size_t)NN_ * D_ * sizeof(float), stream);

    dim3 blk(256);
    detect_mask_k<<<dim3(1), blk, 0, stream>>>((const unsigned int*)mask, flag);
    pack_mask_k<<<dim3(2048), blk, 0, stream>>>(mask, pmask, flag);

    // S1: h1 = leakyrelu(cat(x_i,x_j,eattr) @ W1^T + b1)
    gemm_k<1,false,true,false,false,false><<<dim3(64,4), blk, 0, stream>>>(
        nullptr, W1, b1, nullptr, h1, E_, 256, 768, ei0, ei1, x, eattr, 1.0f);
    // S2: h = h1 @ W2^T + b2
    gemm_k<0,false,false,false,false,false><<<dim3(64,4), blk, 0, stream>>>(
        h1, W2, b2, nullptr, h, E_, 256, 256, nullptr, nullptr, nullptr, nullptr, 1.0f);
    // S3: qkvb = bf16(h @ in_proj_w^T + in_proj_b), q-part scaled by 1/sqrt(32)
    gemm_k<0,false,false,false,false,true><<<dim3(64,12), blk, 0, stream>>>(
        h, ipw, ipb, nullptr, (float*)qkvb, E_, 768, 256, nullptr, nullptr, nullptr, nullptr,
        0.17677669529663687f);
    // V transpose: vt[head][d][key]
    vtrans_k<<<dim3(512), blk, 0, stream>>>(qkvb, vt);
    // S4: MFMA flash attention v2 -> o (f32)
    attn_k<<<dim3(512), blk, 0, stream>>>(qkvb, vt, pmask, o);
    // S5: msg = o @ out_w^T + out_b, scatter-add to aggr[target]
    gemm_k<0,false,false,true,false,false><<<dim3(64,4), blk, 0, stream>>>(
        o, ow, ob, nullptr, aggr, E_, 256, 256, nullptr, ei1, nullptr, nullptr, 1.0f);
    // S6: out = x @ root + aggr + bias_p
    gemm_k<0,true,false,false,true,false><<<dim3(32,4), blk, 0, stream>>>(
        x, root, bp, aggr, outb, NN_, 256, 256, nullptr, nullptr, nullptr, nullptr, 1.0f);
    // LN1
    ln_k<<<dim3(2048), blk, 0, stream>>>(outb, ln1g, ln1b, y1);
    // F2: z = y1 + y1 @ lin_w^T + lin_b
    gemm_k<0,false,false,false,true,false><<<dim3(32,4), blk, 0, stream>>>(
        y1, linw, linb, y1, z, NN_, 256, 256, nullptr, nullptr, nullptr, nullptr, 1.0f);
    // LN2 -> out
    ln_k<<<dim3(2048), blk, 0, stream>>>(z, ln2g, ln2b, (float*)d_out);
}

// Round 7
// 200.048 us; speedup vs baseline: 1.9838x; 1.5618x over previous
//
#include <hip/hip_runtime.h>
#include <hip/hip_bf16.h>
#include <cstdint>

#define D_   256
#define E_   4096
#define NN_  2048

typedef float f32x4_t __attribute__((ext_vector_type(4)));
typedef short bf16x8_t __attribute__((ext_vector_type(8)));

__device__ inline short f2bf(float f) {
    union { float fv; unsigned u; } v; v.fv = f;
    unsigned r = v.u + 0x7fffu + ((v.u >> 16) & 1u);
    return (short)(r >> 16);
}

__device__ inline unsigned cvtpk_bf16(float lo, float hi) {
    unsigned r;
    asm("v_cvt_pk_bf16_f32 %0, %1, %2" : "=v"(r) : "v"(lo), "v"(hi));
    return r;
}

// ---------------------------------------------------------------------------
// bf16 MFMA GEMM: C[M,N] = epi(A[M,K] @ B[N,K]^T + bias). A,B read as f32,
// converted to bf16 inline during LDS staging (cvt_pk). 64x64 tile, 4 waves,
// each wave a 32x32 sub-tile (2x2 16x16 frags), BK=32, dbuf LDS, reg-staged
// prefetch, ONE barrier per K-step (write buf^1 while reading buf: prior
// reads of buf^1 completed at the previous barrier).
// GATHER: A row m = concat(x[ei1[m]], x[ei0[m]], eattr[m]) (K=768).
// SCATTER: f32 atomicAdd into C[ei1[row]*256+col]. OBF16: bf16 store, cols
// <256 scaled by qsc. ACT: LeakyReLU(0.2).
// LDS tiles [64][32] bf16, byte=(row*64+col*2)^((row&7)<<4) both sides.
// ---------------------------------------------------------------------------
template<int ACT, bool GATHER, bool SCATTER, bool OBF16>
__global__ __launch_bounds__(256)
void mgemm_k(const float* __restrict__ A, const float* __restrict__ Bm,
             const float* __restrict__ bias, float* __restrict__ C,
             int M, int N, int K,
             const int* __restrict__ ei0, const int* __restrict__ ei1,
             const float* __restrict__ x, const float* __restrict__ eattr,
             float qsc)
{
    __shared__ char lds[16384];   // As dbuf 2x4KB @0, Bs dbuf 2x4KB @8192
    const int tid = threadIdx.x;
    const int w = tid >> 6, l = tid & 63;
    const int g = l >> 4, ln = l & 15;
    const int wr = w >> 1, wc = w & 1;
    const int m0 = blockIdx.x * 64, n0 = blockIdx.y * 64;

    const int srow = tid >> 2;          // staging row 0..63
    const int sck  = (tid & 3) * 8;     // staging col chunk (8 floats)
    const int sswz = (srow & 7) << 4;
    int gi1 = 0, gi0 = 0;
    if (GATHER) { gi1 = ei1[m0 + srow]; gi0 = ei0[m0 + srow]; }

    f32x4_t acc[2][2];
    #pragma unroll
    for (int m = 0; m < 2; m++)
        #pragma unroll
        for (int n = 0; n < 2; n++)
            acc[m][n] = f32x4_t{0.f, 0.f, 0.f, 0.f};

    const int nt = K >> 5;
    float4 ga0, ga1, gb0, gb1;

    auto loadG = [&](int kk) {
        const int cb = kk + sck;
        const float* src;
        if (GATHER) {
            if (cb < 256)      src = x + (size_t)gi1 * 256 + cb;
            else if (cb < 512) src = x + (size_t)gi0 * 256 + (cb - 256);
            else               src = eattr + (size_t)(m0 + srow) * 256 + (cb - 512);
        } else {
            src = A + (size_t)(m0 + srow) * K + cb;
        }
        ga0 = *(const float4*)src;
        ga1 = *(const float4*)(src + 4);
        const float* bsrc = Bm + (size_t)(n0 + srow) * K + cb;
        gb0 = *(const float4*)bsrc;
        gb1 = *(const float4*)(bsrc + 4);
    };
    auto writeS = [&](int buf) {
        uint4 pa, pb;
        pa.x = cvtpk_bf16(ga0.x, ga0.y); pa.y = cvtpk_bf16(ga0.z, ga0.w);
        pa.z = cvtpk_bf16(ga1.x, ga1.y); pa.w = cvtpk_bf16(ga1.z, ga1.w);
        pb.x = cvtpk_bf16(gb0.x, gb0.y); pb.y = cvtpk_bf16(gb0.z, gb0.w);
        pb.z = cvtpk_bf16(gb1.x, gb1.y); pb.w = cvtpk_bf16(gb1.z, gb1.w);
        const int off = (srow*64 + sck*2) ^ sswz;
        *(uint4*)(lds + buf*4096 + off) = pa;
        *(uint4*)(lds + 8192 + buf*4096 + off) = pb;
    };

    loadG(0);
    writeS(0);
    __syncthreads();
    int cur = 0;
    for (int t = 0; t < nt; ++t) {
        if (t + 1 < nt) loadG((t + 1) << 5);
        bf16x8_t af[2], bfr[2];
        #pragma unroll
        for (int m = 0; m < 2; m++) {
            const int row = wr*32 + m*16 + ln;
            af[m] = *(const bf16x8_t*)(lds + cur*4096 + ((row*64 + g*16) ^ ((row&7)<<4)));
        }
        #pragma unroll
        for (int n = 0; n < 2; n++) {
            const int row = wc*32 + n*16 + ln;
            bfr[n] = *(const bf16x8_t*)(lds + 8192 + cur*4096 + ((row*64 + g*16) ^ ((row&7)<<4)));
        }
        #pragma unroll
        for (int m = 0; m < 2; m++)
            #pragma unroll
            for (int n = 0; n < 2; n++)
                acc[m][n] = __builtin_amdgcn_mfma_f32_16x16x32_bf16(af[m], bfr[n], acc[m][n], 0, 0, 0);
        if (t + 1 < nt) writeS(cur ^ 1);
        __syncthreads();
        cur ^= 1;
    }

    #pragma unroll
    for (int m = 0; m < 2; m++) {
        #pragma unroll
        for (int n = 0; n < 2; n++) {
            const int col = n0 + wc*32 + n*16 + ln;
            const float bv = bias[col];
            #pragma unroll
            for (int r = 0; r < 4; r++) {
                const int row = m0 + wr*32 + m*16 + g*4 + r;
                float v = acc[m][n][r] + bv;
                if (ACT == 1) v = v > 0.f ? v : 0.2f * v;
                if (SCATTER) {
                    atomicAdd(&C[(size_t)ei1[row] * 256 + col], v);
                } else if (OBF16) {
                    ((short*)C)[(size_t)row * N + col] = f2bf((col < 256) ? v * qsc : v);
                } else {
                    C[(size_t)row * N + col] = v;
                }
            }
        }
    }
}

// ---------------------------------------------------------------------------
// Tiled f32 GEMM (kept for S6 x@root BT + F2 residual: exact final path).
// ---------------------------------------------------------------------------
template<int ACT, bool BT, bool HASADD>
__global__ __launch_bounds__(256)
void gemm_k(const float* __restrict__ A, const float* __restrict__ Bm,
            const float* __restrict__ bias, const float* __restrict__ addsrc,
            float* __restrict__ C, int M, int N, int K)
{
    __shared__ float As[64][17];
    __shared__ float Bs[64][17];
    const int tid = threadIdx.x;
    const int m0 = blockIdx.x * 64;
    const int n0 = blockIdx.y * 64;
    const int ty = tid >> 4, tx = tid & 15;
    const int lrow = tid >> 2, lkq = tid & 3;
    float acc[4][4] = {};

    for (int kk = 0; kk < K; kk += 16) {
        {
            const float4 av = *(const float4*)(A + (size_t)(m0 + lrow) * K + kk + lkq * 4);
            As[lrow][lkq*4+0] = av.x; As[lrow][lkq*4+1] = av.y;
            As[lrow][lkq*4+2] = av.z; As[lrow][lkq*4+3] = av.w;
        }
        if (!BT) {
            const float4 bv = *(const float4*)(Bm + (size_t)(n0 + lrow) * K + kk + lkq * 4);
            Bs[lrow][lkq*4+0] = bv.x; Bs[lrow][lkq*4+1] = bv.y;
            Bs[lrow][lkq*4+2] = bv.z; Bs[lrow][lkq*4+3] = bv.w;
        } else {
            #pragma unroll
            for (int r = 0; r < 4; r++) {
                const int idx = tid + r * 256;
                const int kl = idx >> 6, n = idx & 63;
                Bs[n][kl] = Bm[(size_t)(kk + kl) * N + n0 + n];
            }
        }
        __syncthreads();
        #pragma unroll
        for (int k = 0; k < 16; k++) {
            float a[4], b[4];
            #pragma unroll
            for (int i = 0; i < 4; i++) a[i] = As[ty*4+i][k];
            #pragma unroll
            for (int j = 0; j < 4; j++) b[j] = Bs[tx*4+j][k];
            #pragma unroll
            for (int i = 0; i < 4; i++)
                #pragma unroll
                for (int j = 0; j < 4; j++)
                    acc[i][j] = fmaf(a[i], b[j], acc[i][j]);
        }
        __syncthreads();
    }

    #pragma unroll
    for (int i = 0; i < 4; i++) {
        const int m = m0 + ty*4 + i;
        #pragma unroll
        for (int j = 0; j < 4; j++) {
            const int n = n0 + tx*4 + j;
            float v = acc[i][j] + bias[n];
            if (ACT == 1) v = v > 0.f ? v : 0.2f * v;
            if (HASADD) v += addsrc[(size_t)m * N + n];
            C[(size_t)m * N + n] = v;
        }
    }
}

// ---------------------------------------------------------------------------
// Mask dtype detection + bit packing (validated round 2).
// ---------------------------------------------------------------------------
__global__ __launch_bounds__(256)
void detect_mask_k(const unsigned int* __restrict__ m, int* __restrict__ flag)
{
    __shared__ int bad;
    if (threadIdx.x == 0) bad = 0;
    __syncthreads();
    int mybad = 0;
    #pragma unroll
    for (int i = 0; i < 32; i++)
        if (m[threadIdx.x + i * 256] > 1u) mybad = 1;
    if (mybad) atomicOr(&bad, 1);
    __syncthreads();
    if (threadIdx.x == 0) *flag = bad ? 0 : 1;
}

__global__ __launch_bounds__(256)
void pack_mask_k(const unsigned char* __restrict__ mraw,
                 unsigned int* __restrict__ pm, const int* __restrict__ flag)
{
    const int t = blockIdx.x * 256 + threadIdx.x;
    const int row = t >> 7, wb = t & 127;
    unsigned int bits = 0;
    if (*flag) {
        const uint4* p = (const uint4*)((const int*)mraw + (size_t)row * 4096 + wb * 32);
        #pragma unroll
        for (int g = 0; g < 8; g++) {
            const uint4 v = p[g];
            if (v.x) bits |= 1u << (g*4+0);
            if (v.y) bits |= 1u << (g*4+1);
            if (v.z) bits |= 1u << (g*4+2);
            if (v.w) bits |= 1u << (g*4+3);
        }
    } else {
        const uint4* p = (const uint4*)(mraw + (size_t)row * 4096 + wb * 32);
        #pragma unroll
        for (int g = 0; g < 2; g++) {
            const uint4 v = p[g];
            const unsigned int u[4] = {v.x, v.y, v.z, v.w};
            #pragma unroll
            for (int b2 = 0; b2 < 4; b2++)
                #pragma unroll
                for (int by = 0; by < 4; by++)
                    if ((u[b2] >> (8*by)) & 0xffu) bits |= 1u << (g*16 + b2*4 + by);
        }
    }
    pm[t] = bits;
}

// ---------------------------------------------------------------------------
// V pre-transpose: vt[head][d=32][key=4096] bf16 from qkv V-part.
// ---------------------------------------------------------------------------
__global__ __launch_bounds__(256)
void vtrans_k(const short* __restrict__ qkvb, short* __restrict__ vt)
{
    __shared__ short Ts[64][40];
    const int head = blockIdx.x >> 6;
    const int k0 = (blockIdx.x & 63) * 64;
    const int tid = threadIdx.x;
    const int skey = tid >> 2, sc = tid & 3;
    const bf16x8_t v = *(const bf16x8_t*)(qkvb + (size_t)(k0 + skey)*768 + 512 + head*32 + sc*8);
    *(bf16x8_t*)(&Ts[skey][sc*8]) = v;
    __syncthreads();
    const int sd = tid >> 3, skc = tid & 7;
    short outv[8];
    #pragma unroll
    for (int j = 0; j < 8; j++) outv[j] = Ts[skc*8 + j][sd];
    *(bf16x8_t*)(vt + (size_t)head*131072 + (size_t)sd*4096 + k0 + skc*8) = *(bf16x8_t*)outv;
}

// ---------------------------------------------------------------------------
// MFMA bf16 flash attention v2 (validated round 6): swapped QK^T +
// fixed-shift softmax, sequential k-sweep, dbuf K/V staging.
// ---------------------------------------------------------------------------
__global__ __launch_bounds__(256)
void attn_k(const short* __restrict__ qkvb, const short* __restrict__ vt,
            const unsigned int* __restrict__ pmask, float* __restrict__ o)
{
    __shared__ char lds[24576];
    const int tid = threadIdx.x;
    const int w = tid >> 6, l = tid & 63;
    const int g = l >> 4, ln = l & 15;
    const int head = blockIdx.x >> 6;
    const int q0 = (blockIdx.x & 63) * 64;
    const int qa = q0 + w * 16 + ln;

    const bf16x8_t qf = *(const bf16x8_t*)(qkvb + (size_t)qa*768 + head*32 + g*8);

    f32x4_t oT0 = {0.f,0.f,0.f,0.f};
    f32x4_t oT1 = {0.f,0.f,0.f,0.f};
    float lsum = 0.f;

    const int skey = tid >> 2, sc = tid & 3;
    const int sd = tid >> 3, skc = tid & 7;
    const short* kgp = qkvb + 256 + head*32 + sc*8;
    const short* vgp = vt + (size_t)head*131072 + (size_t)sd*4096 + skc*8;
    char* Pw = lds + 16384 + w*2048;
    const unsigned int* mrow = pmask + (size_t)qa*128;
    const int kswz = (skey & 7) << 4, vswz = (sd & 7) << 4;
    const int pswz = (ln & 7) << 4;

    {
        const bf16x8_t kv = *(const bf16x8_t*)(kgp + (size_t)skey*768);
        *(bf16x8_t*)(lds + ((skey*64 + sc*16) ^ kswz)) = kv;
        const bf16x8_t vv = *(const bf16x8_t*)(vgp);
        *(bf16x8_t*)(lds + 8192 + ((sd*128 + skc*16) ^ vswz)) = vv;
    }

    for (int t = 0; t < 64; ++t) {
        __syncthreads();
        const int cur = t & 1;
        if (t < 63) {
            const int k0n = (t + 1) * 64;
            const bf16x8_t kv = *(const bf16x8_t*)(kgp + (size_t)(k0n + skey)*768);
            *(bf16x8_t*)(lds + (cur^1)*4096 + ((skey*64 + sc*16) ^ kswz)) = kv;
            const bf16x8_t vv = *(const bf16x8_t*)(vgp + k0n);
            *(bf16x8_t*)(lds + 8192 + (cur^1)*4096 + ((sd*128 + skc*16) ^ vswz)) = vv;
        }
        char* Kb = lds + cur*4096;
        char* Vb = lds + 8192 + cur*4096;

        f32x4_t s[4];
        #pragma unroll
        for (int kt = 0; kt < 4; kt++) {
            const int key = kt*16 + ln;
            const bf16x8_t kf = *(const bf16x8_t*)(Kb + ((key*64 + g*16) ^ ((key & 7) << 4)));
            f32x4_t z = {0.f,0.f,0.f,0.f};
            s[kt] = __builtin_amdgcn_mfma_f32_16x16x32_bf16(kf, qf, z, 0, 0, 0);
        }

        const uint2 mw = *(const uint2*)(mrow + t*2);
        #pragma unroll
        for (int kt = 0; kt < 4; kt++) {
            const unsigned word = (kt < 2) ? mw.x : mw.y;
            float p[4];
            #pragma unroll
            for (int r = 0; r < 4; r++) {
                const float e = __expf(s[kt][r] - 12.0f);
                p[r] = ((word >> ((kt & 1)*16 + g*4 + r)) & 1u) ? e : 0.f;
            }
            lsum += (p[0] + p[1]) + (p[2] + p[3]);
            uint2 pk;
            pk.x = cvtpk_bf16(p[0], p[1]);
            pk.y = cvtpk_bf16(p[2], p[3]);
            *(uint2*)(Pw + ((ln*128 + kt*32 + g*8) ^ pswz)) = pk;
        }

        #pragma unroll
        for (int kh = 0; kh < 2; kh++) {
            const bf16x8_t pf = *(const bf16x8_t*)(Pw + ((ln*128 + kh*64 + g*16) ^ pswz));
            const bf16x8_t vf0 = *(const bf16x8_t*)(Vb + ((ln*128 + kh*64 + g*16) ^ pswz));
            const bf16x8_t vf1 = *(const bf16x8_t*)(Vb + (((16+ln)*128 + kh*64 + g*16) ^ pswz));
            oT0 = __builtin_amdgcn_mfma_f32_16x16x32_bf16(vf0, pf, oT0, 0, 0, 0);
            oT1 = __builtin_amdgcn_mfma_f32_16x16x32_bf16(vf1, pf, oT1, 0, 0, 0);
        }
    }

    lsum += __shfl_xor(lsum, 16);
    lsum += __shfl_xor(lsum, 32);
    const float inv = 1.0f / fmaxf(lsum, 1e-37f);
    float* op = o + (size_t)qa * 256 + head*32;
    float4 v0 = {oT0[0]*inv, oT0[1]*inv, oT0[2]*inv, oT0[3]*inv};
    float4 v1 = {oT1[0]*inv, oT1[1]*inv, oT1[2]*inv, oT1[3]*inv};
    *(float4*)(op + g*4) = v0;
    *(float4*)(op + 16 + g*4) = v1;
}

// ---------------------------------------------------------------------------
// LayerNorm over 256 dims, one block per row.
// ---------------------------------------------------------------------------
__global__ __launch_bounds__(256)
void ln_k(const float* __restrict__ in, const float* __restrict__ g,
          const float* __restrict__ b, float* __restrict__ out)
{
    const int n = blockIdx.x, t = threadIdx.x;
    const float v = in[(size_t)n * 256 + t];
    float s1 = v, s2 = v * v;
    #pragma unroll
    for (int off = 32; off > 0; off >>= 1) {
        s1 += __shfl_xor(s1, off);
        s2 += __shfl_xor(s2, off);
    }
    __shared__ float r1[4], r2[4];
    const int wv = t >> 6;
    if ((t & 63) == 0) { r1[wv] = s1; r2[wv] = s2; }
    __syncthreads();
    const float t1 = r1[0] + r1[1] + r1[2] + r1[3];
    const float t2 = r2[0] + r2[1] + r2[2] + r2[3];
    const float mu  = t1 * (1.0f / 256.0f);
    const float var = t2 * (1.0f / 256.0f) - mu * mu;
    const float rs  = rsqrtf(var + 1e-5f);
    out[(size_t)n * 256 + t] = (v - mu) * rs * g[t] + b[t];
}

// ---------------------------------------------------------------------------
extern "C" void kernel_launch(void* const* d_in, const int* in_sizes, int n_in,
                              void* d_out, int out_size, void* d_ws, size_t ws_size,
                              hipStream_t stream)
{
    const float* x     = (const float*)d_in[0];
    const int*   ei    = (const int*)  d_in[1];
    const float* eattr = (const float*)d_in[2];
    const unsigned char* mask = (const unsigned char*)d_in[3];
    const float* W1   = (const float*)d_in[4];
    const float* b1   = (const float*)d_in[5];
    const float* W2   = (const float*)d_in[6];
    const float* b2   = (const float*)d_in[7];
    const float* ipw  = (const float*)d_in[8];
    const float* ipb  = (const float*)d_in[9];
    const float* ow   = (const float*)d_in[10];
    const float* ob   = (const float*)d_in[11];
    const float* root = (const float*)d_in[12];
    const float* bp   = (const float*)d_in[13];
    const float* ln1g = (const float*)d_in[14];
    const float* ln1b = (const float*)d_in[15];
    const float* ln2g = (const float*)d_in[16];
    const float* ln2b = (const float*)d_in[17];
    const float* linw = (const float*)d_in[18];
    const float* linb = (const float*)d_in[19];
    const int* ei0 = ei;
    const int* ei1 = ei + E_;

    float* ws = (float*)d_ws;
    float* h1    = ws;                              // [E,256]; later attn o; later z
    float* h     = ws + 1048576;                    // [E,256]; later y1
    short* qkvb  = (short*)(ws + 2097152);          // [E,768] bf16 (q pre-scaled)
    float* aggr  = ws + 3670016;                    // [N,256]
    float* outb  = ws + 4194304;                    // [N,256]
    unsigned int* pmask = (unsigned int*)(ws + 4718592);  // [4096][128] bits
    int* flag    = (int*)(ws + 5242880);
    short* vt    = (short*)(ws + 5242896);          // [8][32][4096] bf16
    float* o    = h1;
    float* y1   = h;
    float* z    = h1;

    hipMemsetAsync(aggr, 0, (size_t)NN_ * D_ * sizeof(float), stream);

    dim3 blk(256);
    detect_mask_k<<<dim3(1), blk, 0, stream>>>((const unsigned int*)mask, flag);
    pack_mask_k<<<dim3(2048), blk, 0, stream>>>(mask, pmask, flag);

    // S1: h1 = leakyrelu(cat(x_i,x_j,eattr) @ W1^T + b1)   [MFMA bf16]
    mgemm_k<1,true,false,false><<<dim3(64,4), blk, 0, stream>>>(
        nullptr, W1, b1, h1, E_, 256, 768, ei0, ei1, x, eattr, 1.0f);
    // S2: h = h1 @ W2^T + b2   [MFMA bf16]
    mgemm_k<0,false,false,false><<<dim3(64,4), blk, 0, stream>>>(
        h1, W2, b2, h, E_, 256, 256, nullptr, nullptr, nullptr, nullptr, 1.0f);
    // S3: qkvb = bf16(h @ in_proj_w^T + in_proj_b), q scaled by 1/sqrt(32)
    mgemm_k<0,false,false,true><<<dim3(64,12), blk, 0, stream>>>(
        h, ipw, ipb, (float*)qkvb, E_, 768, 256, nullptr, nullptr, nullptr, nullptr,
        0.17677669529663687f);
    // V transpose: vt[head][d][key]
    vtrans_k<<<dim3(512), blk, 0, stream>>>(qkvb, vt);
    // S4: MFMA flash attention v2 -> o (f32)
    attn_k<<<dim3(512), blk, 0, stream>>>(qkvb, vt, pmask, o);
    // S5: msg = o @ out_w^T + out_b, scatter-add to aggr   [MFMA bf16]
    mgemm_k<0,false,true,false><<<dim3(64,4), blk, 0, stream>>>(
        o, ow, ob, aggr, E_, 256, 256, nullptr, ei1, nullptr, nullptr, 1.0f);
    // S6: out = x @ root + aggr + bias_p   [f32, exact final path]
    gemm_k<0,true,true><<<dim3(32,4), blk, 0, stream>>>(
        x, root, bp, aggr, outb, NN_, 256, 256);
    // LN1
    ln_k<<<dim3(2048), blk, 0, stream>>>(outb, ln1g, ln1b, y1);
    // F2: z = y1 + y1 @ lin_w^T + lin_b   [f32]
    gemm_k<0,false,true><<<dim3(32,4), blk, 0, stream>>>(
        y1, linw, linb, y1, z, NN_, 256, 256);
    // LN2 -> out
    ln_k<<<dim3(2048), blk, 0, stream>>>(z, ln2g, ln2b, (float*)d_out);
}

// Round 8
// 165.763 us; speedup vs baseline: 2.3941x; 1.2068x over previous
//
#include <hip/hip_runtime.h>
#include <hip/hip_bf16.h>
#include <cstdint>

#define D_   256
#define E_   4096
#define NN_  2048

typedef float f32x4_t __attribute__((ext_vector_type(4)));
typedef short bf16x8_t __attribute__((ext_vector_type(8)));

__device__ inline short f2bf(float f) {
    union { float fv; unsigned u; } v; v.fv = f;
    unsigned r = v.u + 0x7fffu + ((v.u >> 16) & 1u);
    return (short)(r >> 16);
}

__device__ inline unsigned cvtpk_bf16(float lo, float hi) {
    unsigned r;
    asm("v_cvt_pk_bf16_f32 %0, %1, %2" : "=v"(r) : "v"(lo), "v"(hi));
    return r;
}

// ---------------------------------------------------------------------------
// bf16 MFMA GEMM (validated round 7): C = epi(A @ B^T + bias), inline f32->
// bf16 staging, 64x64 tile, 4 waves, BK=32, dbuf, one barrier per K-step.
// ---------------------------------------------------------------------------
template<int ACT, bool GATHER, bool SCATTER, bool OBF16>
__global__ __launch_bounds__(256)
void mgemm_k(const float* __restrict__ A, const float* __restrict__ Bm,
             const float* __restrict__ bias, float* __restrict__ C,
             int M, int N, int K,
             const int* __restrict__ ei0, const int* __restrict__ ei1,
             const float* __restrict__ x, const float* __restrict__ eattr,
             float qsc)
{
    __shared__ char lds[16384];
    const int tid = threadIdx.x;
    const int w = tid >> 6, l = tid & 63;
    const int g = l >> 4, ln = l & 15;
    const int wr = w >> 1, wc = w & 1;
    const int m0 = blockIdx.x * 64, n0 = blockIdx.y * 64;

    const int srow = tid >> 2;
    const int sck  = (tid & 3) * 8;
    const int sswz = (srow & 7) << 4;
    int gi1 = 0, gi0 = 0;
    if (GATHER) { gi1 = ei1[m0 + srow]; gi0 = ei0[m0 + srow]; }

    f32x4_t acc[2][2];
    #pragma unroll
    for (int m = 0; m < 2; m++)
        #pragma unroll
        for (int n = 0; n < 2; n++)
            acc[m][n] = f32x4_t{0.f, 0.f, 0.f, 0.f};

    const int nt = K >> 5;
    float4 ga0, ga1, gb0, gb1;

    auto loadG = [&](int kk) {
        const int cb = kk + sck;
        const float* src;
        if (GATHER) {
            if (cb < 256)      src = x + (size_t)gi1 * 256 + cb;
            else if (cb < 512) src = x + (size_t)gi0 * 256 + (cb - 256);
            else               src = eattr + (size_t)(m0 + srow) * 256 + (cb - 512);
        } else {
            src = A + (size_t)(m0 + srow) * K + cb;
        }
        ga0 = *(const float4*)src;
        ga1 = *(const float4*)(src + 4);
        const float* bsrc = Bm + (size_t)(n0 + srow) * K + cb;
        gb0 = *(const float4*)bsrc;
        gb1 = *(const float4*)(bsrc + 4);
    };
    auto writeS = [&](int buf) {
        uint4 pa, pb;
        pa.x = cvtpk_bf16(ga0.x, ga0.y); pa.y = cvtpk_bf16(ga0.z, ga0.w);
        pa.z = cvtpk_bf16(ga1.x, ga1.y); pa.w = cvtpk_bf16(ga1.z, ga1.w);
        pb.x = cvtpk_bf16(gb0.x, gb0.y); pb.y = cvtpk_bf16(gb0.z, gb0.w);
        pb.z = cvtpk_bf16(gb1.x, gb1.y); pb.w = cvtpk_bf16(gb1.z, gb1.w);
        const int off = (srow*64 + sck*2) ^ sswz;
        *(uint4*)(lds + buf*4096 + off) = pa;
        *(uint4*)(lds + 8192 + buf*4096 + off) = pb;
    };

    loadG(0);
    writeS(0);
    __syncthreads();
    int cur = 0;
    for (int t = 0; t < nt; ++t) {
        if (t + 1 < nt) loadG((t + 1) << 5);
        bf16x8_t af[2], bfr[2];
        #pragma unroll
        for (int m = 0; m < 2; m++) {
            const int row = wr*32 + m*16 + ln;
            af[m] = *(const bf16x8_t*)(lds + cur*4096 + ((row*64 + g*16) ^ ((row&7)<<4)));
        }
        #pragma unroll
        for (int n = 0; n < 2; n++) {
            const int row = wc*32 + n*16 + ln;
            bfr[n] = *(const bf16x8_t*)(lds + 8192 + cur*4096 + ((row*64 + g*16) ^ ((row&7)<<4)));
        }
        #pragma unroll
        for (int m = 0; m < 2; m++)
            #pragma unroll
            for (int n = 0; n < 2; n++)
                acc[m][n] = __builtin_amdgcn_mfma_f32_16x16x32_bf16(af[m], bfr[n], acc[m][n], 0, 0, 0);
        if (t + 1 < nt) writeS(cur ^ 1);
        __syncthreads();
        cur ^= 1;
    }

    #pragma unroll
    for (int m = 0; m < 2; m++) {
        #pragma unroll
        for (int n = 0; n < 2; n++) {
            const int col = n0 + wc*32 + n*16 + ln;
            const float bv = bias[col];
            #pragma unroll
            for (int r = 0; r < 4; r++) {
                const int row = m0 + wr*32 + m*16 + g*4 + r;
                float v = acc[m][n][r] + bv;
                if (ACT == 1) v = v > 0.f ? v : 0.2f * v;
                if (SCATTER) {
                    atomicAdd(&C[(size_t)ei1[row] * 256 + col], v);
                } else if (OBF16) {
                    ((short*)C)[(size_t)row * N + col] = f2bf((col < 256) ? v * qsc : v);
                } else {
                    C[(size_t)row * N + col] = v;
                }
            }
        }
    }
}

// ---------------------------------------------------------------------------
// Tiled f32 GEMM (S6 x@root BT + F2 residual: exact final path).
// ---------------------------------------------------------------------------
template<int ACT, bool BT, bool HASADD>
__global__ __launch_bounds__(256)
void gemm_k(const float* __restrict__ A, const float* __restrict__ Bm,
            const float* __restrict__ bias, const float* __restrict__ addsrc,
            float* __restrict__ C, int M, int N, int K)
{
    __shared__ float As[64][17];
    __shared__ float Bs[64][17];
    const int tid = threadIdx.x;
    const int m0 = blockIdx.x * 64;
    const int n0 = blockIdx.y * 64;
    const int ty = tid >> 4, tx = tid & 15;
    const int lrow = tid >> 2, lkq = tid & 3;
    float acc[4][4] = {};

    for (int kk = 0; kk < K; kk += 16) {
        {
            const float4 av = *(const float4*)(A + (size_t)(m0 + lrow) * K + kk + lkq * 4);
            As[lrow][lkq*4+0] = av.x; As[lrow][lkq*4+1] = av.y;
            As[lrow][lkq*4+2] = av.z; As[lrow][lkq*4+3] = av.w;
        }
        if (!BT) {
            const float4 bv = *(const float4*)(Bm + (size_t)(n0 + lrow) * K + kk + lkq * 4);
            Bs[lrow][lkq*4+0] = bv.x; Bs[lrow][lkq*4+1] = bv.y;
            Bs[lrow][lkq*4+2] = bv.z; Bs[lrow][lkq*4+3] = bv.w;
        } else {
            #pragma unroll
            for (int r = 0; r < 4; r++) {
                const int idx = tid + r * 256;
                const int kl = idx >> 6, n = idx & 63;
                Bs[n][kl] = Bm[(size_t)(kk + kl) * N + n0 + n];
            }
        }
        __syncthreads();
        #pragma unroll
        for (int k = 0; k < 16; k++) {
            float a[4], b[4];
            #pragma unroll
            for (int i = 0; i < 4; i++) a[i] = As[ty*4+i][k];
            #pragma unroll
            for (int j = 0; j < 4; j++) b[j] = Bs[tx*4+j][k];
            #pragma unroll
            for (int i = 0; i < 4; i++)
                #pragma unroll
                for (int j = 0; j < 4; j++)
                    acc[i][j] = fmaf(a[i], b[j], acc[i][j]);
        }
        __syncthreads();
    }

    #pragma unroll
    for (int i = 0; i < 4; i++) {
        const int m = m0 + ty*4 + i;
        #pragma unroll
        for (int j = 0; j < 4; j++) {
            const int n = n0 + tx*4 + j;
            float v = acc[i][j] + bias[n];
            if (ACT == 1) v = v > 0.f ? v : 0.2f * v;
            if (HASADD) v += addsrc[(size_t)m * N + n];
            C[(size_t)m * N + n] = v;
        }
    }
}

// ---------------------------------------------------------------------------
// Mask dtype detection + bit packing (validated round 2).
// ---------------------------------------------------------------------------
__global__ __launch_bounds__(256)
void detect_mask_k(const unsigned int* __restrict__ m, int* __restrict__ flag)
{
    __shared__ int bad;
    if (threadIdx.x == 0) bad = 0;
    __syncthreads();
    int mybad = 0;
    #pragma unroll
    for (int i = 0; i < 32; i++)
        if (m[threadIdx.x + i * 256] > 1u) mybad = 1;
    if (mybad) atomicOr(&bad, 1);
    __syncthreads();
    if (threadIdx.x == 0) *flag = bad ? 0 : 1;
}

__global__ __launch_bounds__(256)
void pack_mask_k(const unsigned char* __restrict__ mraw,
                 unsigned int* __restrict__ pm, const int* __restrict__ flag)
{
    const int t = blockIdx.x * 256 + threadIdx.x;
    const int row = t >> 7, wb = t & 127;
    unsigned int bits = 0;
    if (*flag) {
        const uint4* p = (const uint4*)((const int*)mraw + (size_t)row * 4096 + wb * 32);
        #pragma unroll
        for (int g = 0; g < 8; g++) {
            const uint4 v = p[g];
            if (v.x) bits |= 1u << (g*4+0);
            if (v.y) bits |= 1u << (g*4+1);
            if (v.z) bits |= 1u << (g*4+2);
            if (v.w) bits |= 1u << (g*4+3);
        }
    } else {
        const uint4* p = (const uint4*)(mraw + (size_t)row * 4096 + wb * 32);
        #pragma unroll
        for (int g = 0; g < 2; g++) {
            const uint4 v = p[g];
            const unsigned int u[4] = {v.x, v.y, v.z, v.w};
            #pragma unroll
            for (int b2 = 0; b2 < 4; b2++)
                #pragma unroll
                for (int by = 0; by < 4; by++)
                    if ((u[b2] >> (8*by)) & 0xffu) bits |= 1u << (g*16 + b2*4 + by);
        }
    }
    pm[t] = bits;
}

// ---------------------------------------------------------------------------
// V pre-transpose: vt[head][d=32][key=4096] bf16 from qkv V-part.
// ---------------------------------------------------------------------------
__global__ __launch_bounds__(256)
void vtrans_k(const short* __restrict__ qkvb, short* __restrict__ vt)
{
    __shared__ short Ts[64][40];
    const int head = blockIdx.x >> 6;
    const int k0 = (blockIdx.x & 63) * 64;
    const int tid = threadIdx.x;
    const int skey = tid >> 2, sc = tid & 3;
    const bf16x8_t v = *(const bf16x8_t*)(qkvb + (size_t)(k0 + skey)*768 + 512 + head*32 + sc*8);
    *(bf16x8_t*)(&Ts[skey][sc*8]) = v;
    __syncthreads();
    const int sd = tid >> 3, skc = tid & 7;
    short outv[8];
    #pragma unroll
    for (int j = 0; j < 8; j++) outv[j] = Ts[skc*8 + j][sd];
    *(bf16x8_t*)(vt + (size_t)head*131072 + (size_t)sd*4096 + k0 + skc*8) = *(bf16x8_t*)outv;
}

// ---------------------------------------------------------------------------
// MFMA bf16 flash attention v3: swapped QK^T + fixed-shift softmax +
// IN-BLOCK SPLIT-K x2 with STRIDED tile assignment.
// Block = 64 q x 1 head, 512 thr = 8 waves = 2 key-groups (gi) x 4 q-waves.
// Group gi sweeps tiles tt = 2*i+gi (i=0..31) — both groups stream the same
// L2 window (adjacent tiles in flight), unlike round 5's disjoint ranges.
// Fixed shift => partials merge by PURE ADDITION (l += l', O += O') in LDS.
// Grid 512 blocks -> 2 blocks/CU x 16 waves = 2x wave parallelism vs v2.
// LDS 48KB: K[gi] dbuf @gi*8192, Vt[gi] dbuf @16384+gi*8192, P[w] @32768.
// Merge overlay (after barrier): O[w] @w*2048, l @16384.
// ---------------------------------------------------------------------------
__global__ __launch_bounds__(512, 4)
void attn_k(const short* __restrict__ qkvb, const short* __restrict__ vt,
            const unsigned int* __restrict__ pmask, float* __restrict__ o)
{
    __shared__ char lds[49152];
    const int tid = threadIdx.x;
    const int w2 = tid >> 6, l = tid & 63;
    const int g = l >> 4, ln = l & 15;
    const int gi = w2 >> 2, wq = w2 & 3;
    const int head = blockIdx.x >> 6;
    const int q0 = (blockIdx.x & 63) * 64;
    const int qa = q0 + wq * 16 + ln;

    const bf16x8_t qf = *(const bf16x8_t*)(qkvb + (size_t)qa*768 + head*32 + g*8);

    f32x4_t oT0 = {0.f,0.f,0.f,0.f};
    f32x4_t oT1 = {0.f,0.f,0.f,0.f};
    float lsum = 0.f;

    const int st = tid & 255;                 // staging index within group
    const int skey = st >> 2, sc = st & 3;    // K staging role
    const int sd = st >> 3, skc = st & 7;     // V staging role
    const short* kgp = qkvb + 256 + head*32 + sc*8;
    const short* vgp = vt + (size_t)head*131072 + (size_t)sd*4096 + skc*8;
    char* Kg = lds + gi*8192;
    char* Vg = lds + 16384 + gi*8192;
    char* Pw = lds + 32768 + w2*2048;
    const unsigned int* mrow = pmask + (size_t)qa*128;
    const int kswz = (skey & 7) << 4, vswz = (sd & 7) << 4;
    const int pswz = (ln & 7) << 4;

    {   // stage this group's first tile (tt = gi) -> buf 0
        const int k0 = gi * 64;
        const bf16x8_t kv = *(const bf16x8_t*)(kgp + (size_t)(k0 + skey)*768);
        *(bf16x8_t*)(Kg + ((skey*64 + sc*16) ^ kswz)) = kv;
        const bf16x8_t vv = *(const bf16x8_t*)(vgp + k0);
        *(bf16x8_t*)(Vg + ((sd*128 + skc*16) ^ vswz)) = vv;
    }

    for (int i = 0; i < 32; ++i) {
        __syncthreads();
        const int cur = i & 1;
        const int tt = 2*i + gi;
        if (i < 31) {   // prefetch this group's next tile (tt+2)
            const int k0n = (tt + 2) * 64;
            const bf16x8_t kv = *(const bf16x8_t*)(kgp + (size_t)(k0n + skey)*768);
            *(bf16x8_t*)(Kg + (cur^1)*4096 + ((skey*64 + sc*16) ^ kswz)) = kv;
            const bf16x8_t vv = *(const bf16x8_t*)(vgp + k0n);
            *(bf16x8_t*)(Vg + (cur^1)*4096 + ((sd*128 + skc*16) ^ vswz)) = vv;
        }
        char* Kb = Kg + cur*4096;
        char* Vb = Vg + cur*4096;

        // S^T = mfma(K, Q): col=q=ln, rows = keys kt*16+g*4+r
        f32x4_t s[4];
        #pragma unroll
        for (int kt = 0; kt < 4; kt++) {
            const int key = kt*16 + ln;
            const bf16x8_t kf = *(const bf16x8_t*)(Kb + ((key*64 + g*16) ^ ((key & 7) << 4)));
            f32x4_t z = {0.f,0.f,0.f,0.f};
            s[kt] = __builtin_amdgcn_mfma_f32_16x16x32_bf16(kf, qf, z, 0, 0, 0);
        }

        // fixed-shift masked exp; lsum; pack P -> LDS
        const uint2 mw = *(const uint2*)(mrow + tt*2);
        #pragma unroll
        for (int kt = 0; kt < 4; kt++) {
            const unsigned word = (kt < 2) ? mw.x : mw.y;
            float p[4];
            #pragma unroll
            for (int r = 0; r < 4; r++) {
                const float e = __expf(s[kt][r] - 12.0f);
                p[r] = ((word >> ((kt & 1)*16 + g*4 + r)) & 1u) ? e : 0.f;
            }
            lsum += (p[0] + p[1]) + (p[2] + p[3]);
            uint2 pk;
            pk.x = cvtpk_bf16(p[0], p[1]);
            pk.y = cvtpk_bf16(p[2], p[3]);
            *(uint2*)(Pw + ((ln*128 + kt*32 + g*8) ^ pswz)) = pk;
        }

        // PV: O^T += Vt . P
        #pragma unroll
        for (int kh = 0; kh < 2; kh++) {
            const bf16x8_t pf = *(const bf16x8_t*)(Pw + ((ln*128 + kh*64 + g*16) ^ pswz));
            const bf16x8_t vf0 = *(const bf16x8_t*)(Vb + ((ln*128 + kh*64 + g*16) ^ pswz));
            const bf16x8_t vf1 = *(const bf16x8_t*)(Vb + (((16+ln)*128 + kh*64 + g*16) ^ pswz));
            oT0 = __builtin_amdgcn_mfma_f32_16x16x32_bf16(vf0, pf, oT0, 0, 0, 0);
            oT1 = __builtin_amdgcn_mfma_f32_16x16x32_bf16(vf1, pf, oT1, 0, 0, 0);
        }
    }

    // ---- additive merge of the two key-group partials ----
    __syncthreads();
    *(f32x4_t*)(lds + w2*2048 + l*32)      = oT0;
    *(f32x4_t*)(lds + w2*2048 + l*32 + 16) = oT1;
    ((float*)(lds + 16384))[w2*64 + l] = lsum;
    __syncthreads();
    if (gi == 0) {
        const int pw = w2 + 4;
        const f32x4_t b0 = *(const f32x4_t*)(lds + pw*2048 + l*32);
        const f32x4_t b1 = *(const f32x4_t*)(lds + pw*2048 + l*32 + 16);
        const float lp = ((const float*)(lds + 16384))[pw*64 + l];
        oT0 += b0; oT1 += b1;
        lsum += lp;
        lsum += __shfl_xor(lsum, 16);
        lsum += __shfl_xor(lsum, 32);
        const float inv = 1.0f / fmaxf(lsum, 1e-37f);
        float* op = o + (size_t)qa * 256 + head*32;
        float4 v0 = {oT0[0]*inv, oT0[1]*inv, oT0[2]*inv, oT0[3]*inv};
        float4 v1 = {oT1[0]*inv, oT1[1]*inv, oT1[2]*inv, oT1[3]*inv};
        *(float4*)(op + g*4) = v0;
        *(float4*)(op + 16 + g*4) = v1;
    }
}

// ---------------------------------------------------------------------------
// LayerNorm over 256 dims, one block per row.
// ---------------------------------------------------------------------------
__global__ __launch_bounds__(256)
void ln_k(const float* __restrict__ in, const float* __restrict__ g,
          const float* __restrict__ b, float* __restrict__ out)
{
    const int n = blockIdx.x, t = threadIdx.x;
    const float v = in[(size_t)n * 256 + t];
    float s1 = v, s2 = v * v;
    #pragma unroll
    for (int off = 32; off > 0; off >>= 1) {
        s1 += __shfl_xor(s1, off);
        s2 += __shfl_xor(s2, off);
    }
    __shared__ float r1[4], r2[4];
    const int wv = t >> 6;
    if ((t & 63) == 0) { r1[wv] = s1; r2[wv] = s2; }
    __syncthreads();
    const float t1 = r1[0] + r1[1] + r1[2] + r1[3];
    const float t2 = r2[0] + r2[1] + r2[2] + r2[3];
    const float mu  = t1 * (1.0f / 256.0f);
    const float var = t2 * (1.0f / 256.0f) - mu * mu;
    const float rs  = rsqrtf(var + 1e-5f);
    out[(size_t)n * 256 + t] = (v - mu) * rs * g[t] + b[t];
}

// ---------------------------------------------------------------------------
extern "C" void kernel_launch(void* const* d_in, const int* in_sizes, int n_in,
                              void* d_out, int out_size, void* d_ws, size_t ws_size,
                              hipStream_t stream)
{
    const float* x     = (const float*)d_in[0];
    const int*   ei    = (const int*)  d_in[1];
    const float* eattr = (const float*)d_in[2];
    const unsigned char* mask = (const unsigned char*)d_in[3];
    const float* W1   = (const float*)d_in[4];
    const float* b1   = (const float*)d_in[5];
    const float* W2   = (const float*)d_in[6];
    const float* b2   = (const float*)d_in[7];
    const float* ipw  = (const float*)d_in[8];
    const float* ipb  = (const float*)d_in[9];
    const float* ow   = (const float*)d_in[10];
    const float* ob   = (const float*)d_in[11];
    const float* root = (const float*)d_in[12];
    const float* bp   = (const float*)d_in[13];
    const float* ln1g = (const float*)d_in[14];
    const float* ln1b = (const float*)d_in[15];
    const float* ln2g = (const float*)d_in[16];
    const float* ln2b = (const float*)d_in[17];
    const float* linw = (const float*)d_in[18];
    const float* linb = (const float*)d_in[19];
    const int* ei0 = ei;
    const int* ei1 = ei + E_;

    float* ws = (float*)d_ws;
    float* h1    = ws;                              // [E,256]; later attn o; later z
    float* h     = ws + 1048576;                    // [E,256]; later y1
    short* qkvb  = (short*)(ws + 2097152);          // [E,768] bf16 (q pre-scaled)
    float* aggr  = ws + 3670016;                    // [N,256]
    float* outb  = ws + 4194304;                    // [N,256]
    unsigned int* pmask = (unsigned int*)(ws + 4718592);  // [4096][128] bits
    int* flag    = (int*)(ws + 5242880);
    short* vt    = (short*)(ws + 5242896);          // [8][32][4096] bf16
    float* o    = h1;
    float* y1   = h;
    float* z    = h1;

    hipMemsetAsync(aggr, 0, (size_t)NN_ * D_ * sizeof(float), stream);

    dim3 blk(256);
    detect_mask_k<<<dim3(1), blk, 0, stream>>>((const unsigned int*)mask, flag);
    pack_mask_k<<<dim3(2048), blk, 0, stream>>>(mask, pmask, flag);

    // S1: h1 = leakyrelu(cat(x_i,x_j,eattr) @ W1^T + b1)   [MFMA bf16]
    mgemm_k<1,true,false,false><<<dim3(64,4), blk, 0, stream>>>(
        nullptr, W1, b1, h1, E_, 256, 768, ei0, ei1, x, eattr, 1.0f);
    // S2: h = h1 @ W2^T + b2   [MFMA bf16]
    mgemm_k<0,false,false,false><<<dim3(64,4), blk, 0, stream>>>(
        h1, W2, b2, h, E_, 256, 256, nullptr, nullptr, nullptr, nullptr, 1.0f);
    // S3: qkvb = bf16(h @ in_proj_w^T + in_proj_b), q scaled by 1/sqrt(32)
    mgemm_k<0,false,false,true><<<dim3(64,12), blk, 0, stream>>>(
        h, ipw, ipb, (float*)qkvb, E_, 768, 256, nullptr, nullptr, nullptr, nullptr,
        0.17677669529663687f);
    // V transpose: vt[head][d][key]
    vtrans_k<<<dim3(512), blk, 0, stream>>>(qkvb, vt);
    // S4: MFMA flash attention v3 (in-block split-K x2) -> o (f32)
    attn_k<<<dim3(512), dim3(512), 0, stream>>>(qkvb, vt, pmask, o);
    // S5: msg = o @ out_w^T + out_b, scatter-add to aggr   [MFMA bf16]
    mgemm_k<0,false,true,false><<<dim3(64,4), blk, 0, stream>>>(
        o, ow, ob, aggr, E_, 256, 256, nullptr, ei1, nullptr, nullptr, 1.0f);
    // S6: out = x @ root + aggr + bias_p   [f32, exact final path]
    gemm_k<0,true,true><<<dim3(32,4), blk, 0, stream>>>(
        x, root, bp, aggr, outb, NN_, 256, 256);
    // LN1
    ln_k<<<dim3(2048), blk, 0, stream>>>(outb, ln1g, ln1b, y1);
    // F2: z = y1 + y1 @ lin_w^T + lin_b   [f32]
    gemm_k<0,false,true><<<dim3(32,4), blk, 0, stream>>>(
        y1, linw, linb, y1, z, NN_, 256, 256);
    // LN2 -> out
    ln_k<<<dim3(2048), blk, 0, stream>>>(z, ln2g, ln2b, (float*)d_out);
}